// Round 11
// baseline (373.457 us; speedup 1.0000x reference)
//
#include <hip/hip_runtime.h>

#define N_NODES 50000
#define N_EDGES 800000
#define NP 50048          // N padded
#define BKT 784           // nodes per bucket (64 buckets x 784 = 50176 >= N)
#define NBKT 64
#define BREG 16384        // fixed edge-region per bucket (mean 12500, sigma ~111 -> ~35 sigma)
#define HB 782            // scatter blocks: 782*1024 >= 800000
#define PADK 136          // 128 + 8 bf16 pad
#define NCOPY 64          // BN-stat replication
#define WPB 512           // wprep blocks

typedef __bf16 bf16_8 __attribute__((ext_vector_type(8)));
typedef float  f32_4  __attribute__((ext_vector_type(4)));

__device__ inline float2 bf2f2(unsigned int u) {
    union { unsigned int i; float f; } a, b;
    a.i = u << 16;
    b.i = u & 0xffff0000u;
    return make_float2(a.f, b.f);
}

// ---------------- init (colpart/out_head/cursor) + weight transpose + svec ----------------
__global__ void k_init_wprep(float* __restrict__ colpart, float* __restrict__ out_head,
                             int* __restrict__ cursor,
                             const float* __restrict__ conv_w, const float* __restrict__ lin1_w,
                             __bf16* __restrict__ WT, float* __restrict__ svec) {
    int b = blockIdx.x;
    if (b < 64) {
        int i = b * 256 + threadIdx.x;        // 64*256 = 16384 = 2*NCOPY*128
        colpart[i] = 0.f;
        if (i < 32) out_head[i] = 0.f;
        if (i < NBKT) cursor[i] = 0;
    } else if (b < 64 + WPB) {
        int b2 = b - 64;                      // 0..511
        int mat = b2 >> 7, n = b2 & 127, k = threadIdx.x;
        if (k < 128) {
            const float* srcm = (mat < 3) ? (conv_w + (size_t)mat * 16384) : lin1_w;
            WT[((size_t)mat * 128 + n) * 128 + k] = (__bf16)srcm[(size_t)k * 128 + n];
        }
    } else {
        int j = threadIdx.x;                  // svec = colsum of lin1_w rows 256..511
        if (j < 128) {
            float s = 0.f;
            for (int k = 256; k < 512; ++k) s += lin1_w[(size_t)k * 128 + j];
            svec[j] = s;
        }
    }
}

// ---------------- CSR build pass 1: bucket scatter w/ dynamic cursor reservation ----------------
__global__ __launch_bounds__(256) void k_scatter(const int* __restrict__ src,
                                                 const int* __restrict__ dst,
                                                 const float* __restrict__ ew,
                                                 int* __restrict__ cursor,
                                                 uint2* __restrict__ ebuf) {
    __shared__ int c[NBKT], basee[NBKT];
    int t = threadIdx.x, b = blockIdx.x;
    if (t < NBKT) c[t] = 0;
    __syncthreads();
    int e0 = b * 1024;
    int myd[4], mybkt[4];
#pragma unroll
    for (int j = 0; j < 4; ++j) {
        int e = e0 + t + j * 256;
        mybkt[j] = -1;
        if (e < N_EDGES) {
            myd[j] = dst[e];
            mybkt[j] = myd[j] / BKT;
            atomicAdd(&c[mybkt[j]], 1);
        }
    }
    __syncthreads();
    if (t < NBKT && c[t] > 0) basee[t] = atomicAdd(&cursor[t], c[t]);
    __syncthreads();
    if (t < NBKT) c[t] = 0;   // reuse as local fill
    __syncthreads();
#pragma unroll
    for (int j = 0; j < 4; ++j) {
        if (mybkt[j] >= 0) {
            int e = e0 + t + j * 256;
            int bkt = mybkt[j];
            int dl = myd[j] - bkt * BKT;                 // < 784
            int pos = basee[bkt] + atomicAdd(&c[bkt], 1);
            ebuf[(size_t)bkt * BREG + pos] =
                make_uint2(((unsigned)dl << 17) | (unsigned)src[e], __float_as_uint(ew[e]));
        }
    }
}

// ---------------- CSR build pass 2: one block per bucket -> per-node CSR + dinv -----------------
__global__ __launch_bounds__(256) void k_build(const uint2* __restrict__ ebuf,
                                               const int* __restrict__ cursor,
                                               uint2* __restrict__ esn2,
                                               int* __restrict__ offs, int* __restrict__ cnt,
                                               float* __restrict__ dinv) {
    __shared__ int   c784[1024];
    __shared__ float deg784[1024];
    __shared__ int   o784[1024];
    __shared__ int   fill784[1024];
    __shared__ int   p[256];
    int b = blockIdx.x, t = threadIdx.x;
    size_t base = (size_t)b * BREG;
    int num = cursor[b];
    for (int i = t; i < 1024; i += 256) { c784[i] = 0; deg784[i] = 1.0f; fill784[i] = 0; }
    __syncthreads();
    for (int i = t; i < num; i += 256) {
        uint2 eu = ebuf[base + i];
        int dl = eu.x >> 17;
        atomicAdd(&c784[dl], 1);
        atomicAdd(&deg784[dl], __uint_as_float(eu.y));   // LDS float atomic
    }
    __syncthreads();
    for (int i = t; i < BKT; i += 256) deg784[i] = rsqrtf(deg784[i]);   // now holds dinv
    int s0 = c784[4 * t] + c784[4 * t + 1] + c784[4 * t + 2] + c784[4 * t + 3];
    p[t] = s0;
    __syncthreads();
    int own = s0;
    for (int d = 1; d < 256; d <<= 1) {
        int v = (t >= d) ? p[t - d] : 0;
        __syncthreads();
        p[t] += v;
        __syncthreads();
    }
    int e0 = p[t] - own;
    o784[4 * t] = e0;
    o784[4 * t + 1] = e0 + c784[4 * t];
    o784[4 * t + 2] = e0 + c784[4 * t] + c784[4 * t + 1];
    o784[4 * t + 3] = e0 + c784[4 * t] + c784[4 * t + 1] + c784[4 * t + 2];
    __syncthreads();
    int nb0 = b * BKT;
    for (int i = t; i < BKT; i += 256) {
        int n = nb0 + i;
        if (n < N_NODES) {
            offs[n] = (int)base + o784[i];
            cnt[n] = c784[i];
            dinv[n] = deg784[i];
        }
    }
    __syncthreads();
    for (int i = t; i < num; i += 256) {
        uint2 eu = ebuf[base + i];
        int dl = eu.x >> 17;
        int s  = (int)(eu.x & 131071u);
        int pos = (int)base + o784[dl] + atomicAdd(&fill784[dl], 1);
        esn2[pos] = make_uint2((unsigned)s,
                               __float_as_uint(__uint_as_float(eu.y) * deg784[dl]));
    }
}

// ---------------- MFMA GEMM: C[n][128] = A'[n][128] @ W + bias ----------------
// AMODE 0: A = raw fp32 (x). AMODE 1: A = fp32 agg, fused BN+relu.
template <int AMODE>
__global__ __launch_bounds__(256) void k_gemm_mfma(const float* __restrict__ A,
                                                   const float* __restrict__ mean,
                                                   const float* __restrict__ rstd,
                                                   const __bf16* __restrict__ WT,
                                                   const float* __restrict__ bias,
                                                   __bf16* __restrict__ C, int nrows) {
    __shared__ __bf16 As[64 * PADK];
    __shared__ __bf16 Ws[128 * PADK];
    int t = threadIdx.x;
    int rowBase = blockIdx.x * 64;
    const uint4* WTg = (const uint4*)WT;
    for (int i = t; i < 2048; i += 256) {
        int n = i >> 4, k8 = i & 15;
        *(uint4*)&Ws[n * PADK + k8 * 8] = WTg[i];
    }
    const float4* A4 = (const float4*)A;
    const float4* M4 = (const float4*)mean;
    const float4* R4 = (const float4*)rstd;
    for (int i = t; i < 1024; i += 256) {
        int r = i >> 4, k8 = i & 15;
        int gr = rowBase + r;
        float4 a0 = make_float4(0.f, 0.f, 0.f, 0.f), a1 = a0;
        if (gr < nrows) {
            a0 = A4[(size_t)gr * 32 + k8 * 2];
            a1 = A4[(size_t)gr * 32 + k8 * 2 + 1];
        }
        if (AMODE == 1) {
            float4 m0 = M4[k8 * 2], m1 = M4[k8 * 2 + 1];
            float4 r0 = R4[k8 * 2], r1 = R4[k8 * 2 + 1];
            a0.x = fmaxf((a0.x - m0.x) * r0.x, 0.f); a0.y = fmaxf((a0.y - m0.y) * r0.y, 0.f);
            a0.z = fmaxf((a0.z - m0.z) * r0.z, 0.f); a0.w = fmaxf((a0.w - m0.w) * r0.w, 0.f);
            a1.x = fmaxf((a1.x - m1.x) * r1.x, 0.f); a1.y = fmaxf((a1.y - m1.y) * r1.y, 0.f);
            a1.z = fmaxf((a1.z - m1.z) * r1.z, 0.f); a1.w = fmaxf((a1.w - m1.w) * r1.w, 0.f);
        }
        bf16_8 o = { (__bf16)a0.x, (__bf16)a0.y, (__bf16)a0.z, (__bf16)a0.w,
                     (__bf16)a1.x, (__bf16)a1.y, (__bf16)a1.z, (__bf16)a1.w };
        *(bf16_8*)&As[r * PADK + k8 * 8] = o;
    }
    __syncthreads();
    int wave = t >> 6, lane = t & 63, quad = lane >> 4, m = lane & 15;
    int ar = wave * 16 + m;
    f32_4 acc[8];
#pragma unroll
    for (int i = 0; i < 8; ++i) acc[i] = (f32_4){0.f, 0.f, 0.f, 0.f};
#pragma unroll
    for (int kk = 0; kk < 4; ++kk) {
        bf16_8 a = *(const bf16_8*)&As[ar * PADK + kk * 32 + quad * 8];
#pragma unroll
        for (int n0 = 0; n0 < 8; ++n0) {
            bf16_8 b = *(const bf16_8*)&Ws[(n0 * 16 + m) * PADK + kk * 32 + quad * 8];
            acc[n0] = __builtin_amdgcn_mfma_f32_16x16x32_bf16(a, b, acc[n0], 0, 0, 0);
        }
    }
    __syncthreads();
#pragma unroll
    for (int n0 = 0; n0 < 8; ++n0) {
        int col = n0 * 16 + m;
        float bi = bias[col];
#pragma unroll
        for (int r = 0; r < 4; ++r) {
            int rr = wave * 16 + quad * 4 + r;
            As[rr * PADK + col] = (__bf16)(acc[n0][r] + bi);
        }
    }
    __syncthreads();
    uint4* Cg = (uint4*)C;
    for (int i = t; i < 1024; i += 256) {
        int r = i >> 4, k8 = i & 15;
        int gr = rowBase + r;
        if (gr < nrows) Cg[(size_t)gr * 16 + k8] = *(const uint4*)&As[r * PADK + k8 * 8];
    }
}

// ---------------- edge aggregation (unroll 8, chunked) + fused BN stats -------------------------
__global__ __launch_bounds__(256) void k_agg(const __bf16* __restrict__ hwb,
                                             const uint2* __restrict__ esn2,
                                             const int* __restrict__ offs,
                                             const int* __restrict__ cnt,
                                             const float* __restrict__ dinv,
                                             float* __restrict__ agg,
                                             float* __restrict__ colpart) {
    __shared__ float red1[4 * 128], red2[4 * 128];
    int t = threadIdx.x;
    int n = (blockIdx.x * 256 + t) >> 6;
    int lane = t & 63, wave = t >> 6;
    float2 acc = make_float2(0.f, 0.f);
    const unsigned int* hw32 = (const unsigned int*)hwb;
    if (n < N_NODES) {
        float dvn = dinv[n];
        float2 sv = bf2f2(hw32[(size_t)n * 64 + lane]);
        acc.x = sv.x * dvn * dvn; acc.y = sv.y * dvn * dvn;   // self-loop term
        int beg = offs[n], num = cnt[n];
        for (int ch = 0; ch < num; ch += 64) {
            int nn = min(64, num - ch);
            int s_l = 0; float w_l = 0.f;
            if (lane < nn) {
                uint2 e = esn2[beg + ch + lane];
                s_l = (int)e.x;
                w_l = dinv[s_l] * __uint_as_float(e.y);       // e.y = ew*dinv[dst]
            }
            int i = 0;
            for (; i + 8 <= nn; i += 8) {
                int ss[8]; float ww[8]; unsigned uu[8];
#pragma unroll
                for (int j = 0; j < 8; ++j) { ss[j] = __shfl(s_l, i + j); ww[j] = __shfl(w_l, i + j); }
#pragma unroll
                for (int j = 0; j < 8; ++j) uu[j] = hw32[(size_t)ss[j] * 64 + lane];
#pragma unroll
                for (int j = 0; j < 8; ++j) {
                    float2 f = bf2f2(uu[j]);
                    acc.x += f.x * ww[j]; acc.y += f.y * ww[j];
                }
            }
            for (; i < nn; ++i) {
                int s = __shfl(s_l, i);
                float w = __shfl(w_l, i);
                float2 f = bf2f2(hw32[(size_t)s * 64 + lane]);
                acc.x += f.x * w; acc.y += f.y * w;
            }
        }
        ((float2*)agg)[(size_t)n * 64 + lane] = acc;
    }
    *(float2*)&red1[wave * 128 + 2 * lane] = acc;
    *(float2*)&red2[wave * 128 + 2 * lane] = make_float2(acc.x * acc.x, acc.y * acc.y);
    __syncthreads();
    if (t < 128) {
        float s = red1[t] + red1[128 + t] + red1[256 + t] + red1[384 + t];
        float q = red2[t] + red2[128 + t] + red2[256 + t] + red2[384 + t];
        int c = blockIdx.x & (NCOPY - 1);
        unsafeAtomicAdd(&colpart[c * 128 + t], s);
        unsafeAtomicAdd(&colpart[NCOPY * 128 + c * 128 + t], q);
    }
}

// ---------------- bnfinal (parallel, 256 thr) + optional fused scoring-prep (layer 2) -----------
// Separate launch = cross-XCD visibility for colpart (R7 lesson).
template <int DO_PREP>
__global__ void k_bnfinal(float* __restrict__ colpart, float* __restrict__ mean,
                          float* __restrict__ rstd,
                          const float* __restrict__ agg, const int* __restrict__ cid,
                          const float* __restrict__ lin1w, const float* __restrict__ lin1b,
                          float* __restrict__ c0) {
    __shared__ float s1[256], s2[256], ms[128], rs[128], xc[128];
    int t = threadIdx.x;
    int j = t & 127, g = t >> 7;              // g in {0,1}: 32 copies each
    float s = 0.f, q = 0.f;
    for (int c = g * 32; c < g * 32 + 32; ++c) {
        s += colpart[c * 128 + j];
        q += colpart[NCOPY * 128 + c * 128 + j];
        colpart[c * 128 + j] = 0.f;           // ready for next layer
        colpart[NCOPY * 128 + c * 128 + j] = 0.f;
    }
    s1[t] = s; s2[t] = q;
    __syncthreads();
    if (t < 128) {
        float S = s1[t] + s1[t + 128];
        float Q = s2[t] + s2[t + 128];
        float m = S * (1.0f / N_NODES);
        float v = Q * (1.0f / N_NODES) - m * m;
        float r = rsqrtf(v + 1e-5f);
        mean[t] = m; rstd[t] = r;
        if (DO_PREP) { ms[t] = m; rs[t] = r; }
    }
    if (DO_PREP) {
        __syncthreads();
        int cn = cid[0];
        if (t < 128) xc[t] = fmaxf((agg[(size_t)cn * 128 + t] - ms[t]) * rs[t], 0.f);
        __syncthreads();
        float acc = g ? 0.f : lin1b[j];
        for (int k = g * 64; k < g * 64 + 64; ++k)
            acc += xc[k] * lin1w[(size_t)(128 + k) * 128 + j];
        s1[t] = acc;
        __syncthreads();
        if (t < 128) c0[t] = s1[t] + s1[t + 128];
    }
}

// ---------------- scoring: fused BN+relu staging (writes fp32 h) + MFMA + relu + dot(lin2)
//                  + fused partition pooling epilogue ------------------------------------------
__global__ __launch_bounds__(256) void k_score_mfma(const float* __restrict__ agg,
                                                    const float* __restrict__ mean,
                                                    const float* __restrict__ rstd,
                                                    const __bf16* __restrict__ WT,
                                                    const float* __restrict__ c0,
                                                    const float* __restrict__ svec,
                                                    const float* __restrict__ ecn,
                                                    const float* __restrict__ lin2w,
                                                    const float* __restrict__ lin2b,
                                                    const float* __restrict__ part,
                                                    float* __restrict__ out,
                                                    float* __restrict__ hout,
                                                    int nrows) {
    __shared__ __bf16 As[64 * PADK];
    __shared__ __bf16 Ws[128 * PADK];
    __shared__ float c0s[128], svs[128], l2s[128];
    __shared__ float sc[64], red[256];
    int t = threadIdx.x;
    int rowBase = blockIdx.x * 64;
    const uint4* WTg = (const uint4*)WT;
    for (int i = t; i < 2048; i += 256) {
        int n = i >> 4, k8 = i & 15;
        *(uint4*)&Ws[n * PADK + k8 * 8] = WTg[i];
    }
    const float4* A4 = (const float4*)agg;
    const float4* M4 = (const float4*)mean;
    const float4* R4 = (const float4*)rstd;
    float4* H4 = (float4*)hout;
    for (int i = t; i < 1024; i += 256) {
        int r = i >> 4, k8 = i & 15;
        int gr = rowBase + r;
        float4 a0 = make_float4(0.f, 0.f, 0.f, 0.f), a1 = a0;
        if (gr < nrows) {
            a0 = A4[(size_t)gr * 32 + k8 * 2];
            a1 = A4[(size_t)gr * 32 + k8 * 2 + 1];
        }
        float4 m0 = M4[k8 * 2], m1 = M4[k8 * 2 + 1];
        float4 r0 = R4[k8 * 2], r1 = R4[k8 * 2 + 1];
        float4 f0, f1;
        f0.x = fmaxf((a0.x - m0.x) * r0.x, 0.f); f0.y = fmaxf((a0.y - m0.y) * r0.y, 0.f);
        f0.z = fmaxf((a0.z - m0.z) * r0.z, 0.f); f0.w = fmaxf((a0.w - m0.w) * r0.w, 0.f);
        f1.x = fmaxf((a1.x - m1.x) * r1.x, 0.f); f1.y = fmaxf((a1.y - m1.y) * r1.y, 0.f);
        f1.z = fmaxf((a1.z - m1.z) * r1.z, 0.f); f1.w = fmaxf((a1.w - m1.w) * r1.w, 0.f);
        if (gr < nrows) {
            H4[(size_t)gr * 32 + k8 * 2] = f0;
            H4[(size_t)gr * 32 + k8 * 2 + 1] = f1;
        }
        bf16_8 o = { (__bf16)f0.x, (__bf16)f0.y, (__bf16)f0.z, (__bf16)f0.w,
                     (__bf16)f1.x, (__bf16)f1.y, (__bf16)f1.z, (__bf16)f1.w };
        *(bf16_8*)&As[r * PADK + k8 * 8] = o;
    }
    if (t < 128) { c0s[t] = c0[t]; svs[t] = svec[t]; l2s[t] = lin2w[t]; }
    __syncthreads();
    int wave = t >> 6, lane = t & 63, quad = lane >> 4, m = lane & 15;
    int ar = wave * 16 + m;
    f32_4 acc[8];
#pragma unroll
    for (int i = 0; i < 8; ++i) acc[i] = (f32_4){0.f, 0.f, 0.f, 0.f};
#pragma unroll
    for (int kk = 0; kk < 4; ++kk) {
        bf16_8 a = *(const bf16_8*)&As[ar * PADK + kk * 32 + quad * 8];
#pragma unroll
        for (int n0 = 0; n0 < 8; ++n0) {
            bf16_8 b = *(const bf16_8*)&Ws[(n0 * 16 + m) * PADK + kk * 32 + quad * 8];
            acc[n0] = __builtin_amdgcn_mfma_f32_16x16x32_bf16(a, b, acc[n0], 0, 0, 0);
        }
    }
    float l2b = lin2b[0];
#pragma unroll
    for (int r = 0; r < 4; ++r) {
        int row = rowBase + wave * 16 + quad * 4 + r;
        float e = (row < nrows) ? ecn[row] : 0.f;
        float partial = 0.f;
#pragma unroll
        for (int n0 = 0; n0 < 8; ++n0) {
            int col = n0 * 16 + m;
            float v = acc[n0][r] + c0s[col] + e * svs[col];
            partial += fmaxf(v, 0.f) * l2s[col];
        }
        partial += __shfl_xor(partial, 8, 16);
        partial += __shfl_xor(partial, 4, 16);
        partial += __shfl_xor(partial, 2, 16);
        partial += __shfl_xor(partial, 1, 16);
        if (m == 0) sc[wave * 16 + quad * 4 + r] = partial + l2b;
    }
    __syncthreads();
    // fused partition pooling: out[p] += sum_r sc[r]*part[row][p]
    int rg = t >> 5, pp = t & 31;
    float a = 0.f;
    for (int j = 0; j < 8; ++j) {
        int r = rg * 8 + j;
        int row = rowBase + r;
        if (row < nrows) a += sc[r] * part[(size_t)row * 32 + pp];
    }
    red[t] = a;
    __syncthreads();
    if (t < 32) {
        float s = 0.f;
        for (int i = 0; i < 8; ++i) s += red[i * 32 + t];
        unsafeAtomicAdd(&out[t], s);
    }
}

// ---------------- host ----------------
extern "C" void kernel_launch(void* const* d_in, const int* in_sizes, int n_in,
                              void* d_out, int out_size, void* d_ws, size_t ws_size,
                              hipStream_t stream) {
    const float* x        = (const float*)d_in[0];
    const int*   eidx     = (const int*)d_in[1];
    const float* ew       = (const float*)d_in[2];
    const float* parts    = (const float*)d_in[3];
    const float* ecn      = (const float*)d_in[5];
    const float* conv_w   = (const float*)d_in[6];
    const float* conv_b   = (const float*)d_in[7];
    const float* lin1_w   = (const float*)d_in[8];
    const float* lin1_b   = (const float*)d_in[9];
    const float* lin2_w   = (const float*)d_in[10];
    const float* lin2_b   = (const float*)d_in[11];
    const int*   cid      = (const int*)d_in[12];

    const int* src = eidx;
    const int* dst = eidx + N_EDGES;

    char* p = (char*)d_ws;
    auto alloc = [&](size_t bytes) { char* r = p; p += (bytes + 255) & ~size_t(255); return r; };
    int*    cursor  = (int*)alloc(NBKT * 4);
    uint2*  ebuf    = (uint2*)alloc((size_t)NBKT * BREG * 8);       // 8.4 MB bucket regions
    uint2*  esn2    = (uint2*)alloc((size_t)NBKT * BREG * 8);       // 8.4 MB node-sorted CSR
    int*    offs    = (int*)alloc(NP * 4);
    int*    cnt     = (int*)alloc(NP * 4);
    float*  dinv    = (float*)alloc(NP * 4);
    float*  colpart = (float*)alloc(2 * NCOPY * 128 * 4);
    float*  mean    = (float*)alloc(128 * 4);
    float*  rstd    = (float*)alloc(128 * 4);
    float*  c0      = (float*)alloc(128 * 4);
    float*  svec    = (float*)alloc(128 * 4);
    __bf16* WT      = (__bf16*)alloc(4 * 128 * 128 * 2);
    __bf16* hwb     = (__bf16*)alloc((size_t)N_NODES * 128 * 2);
    float*  agg     = (float*)alloc((size_t)N_NODES * 128 * 4);

    float* out_head = (float*)d_out;
    float* hbuf     = (float*)d_out + 32;

    const int GB = (N_NODES + 63) / 64;        // 782
    const int AB = (N_NODES * 64 + 255) / 256; // 12500

    k_init_wprep<<<64 + WPB + 1, 256, 0, stream>>>(colpart, out_head, cursor,
                                                   conv_w, lin1_w, WT, svec);
    k_scatter<<<HB, 256, 0, stream>>>(src, dst, ew, cursor, ebuf);
    k_build<<<NBKT, 256, 0, stream>>>(ebuf, cursor, esn2, offs, cnt, dinv);

    for (int l = 0; l < 3; ++l) {
        if (l == 0)
            k_gemm_mfma<0><<<GB, 256, 0, stream>>>(x, mean, rstd, WT, conv_b, hwb, N_NODES);
        else
            k_gemm_mfma<1><<<GB, 256, 0, stream>>>(agg, mean, rstd, WT + (size_t)l * 16384,
                                                   conv_b + (size_t)l * 128, hwb, N_NODES);
        k_agg<<<AB, 256, 0, stream>>>(hwb, esn2, offs, cnt, dinv, agg, colpart);
        if (l < 2)
            k_bnfinal<0><<<1, 256, 0, stream>>>(colpart, mean, rstd,
                                                agg, cid, lin1_w, lin1_b, c0);
        else
            k_bnfinal<1><<<1, 256, 0, stream>>>(colpart, mean, rstd,
                                                agg, cid, lin1_w, lin1_b, c0);
    }

    k_score_mfma<<<GB, 256, 0, stream>>>(agg, mean, rstd, WT + (size_t)3 * 16384, c0, svec,
                                         ecn, lin2_w, lin2_b, parts, out_head, hbuf, N_NODES);
}

// Round 12
// 358.132 us; speedup vs baseline: 1.0428x; 1.0428x over previous
//
#include <hip/hip_runtime.h>

#define N_NODES 50000
#define N_EDGES 800000
#define NP 50048          // N padded
#define BKT 392           // nodes per bucket (128 buckets x 392 = 50176 >= N)
#define NBKT 128
#define BREG 8192         // fixed edge-region per bucket (mean 6250, sigma ~79 -> ~24 sigma)
#define SCAP 7168         // LDS staging capacity in k_build (mean+11.6 sigma)
#define HB 782            // scatter blocks: 782*1024 >= 800000
#define PADK 136          // 128 + 8 bf16 pad
#define NCOPY 64          // BN-stat replication
#define WPB 512           // wprep blocks

typedef __bf16 bf16_8 __attribute__((ext_vector_type(8)));
typedef float  f32_4  __attribute__((ext_vector_type(4)));

__device__ inline float2 bf2f2(unsigned int u) {
    union { unsigned int i; float f; } a, b;
    a.i = u << 16;
    b.i = u & 0xffff0000u;
    return make_float2(a.f, b.f);
}

// ---------------- init (colpart/out_head/cursor) + weight transpose + svec ----------------
__global__ void k_init_wprep(float* __restrict__ colpart, float* __restrict__ out_head,
                             int* __restrict__ cursor,
                             const float* __restrict__ conv_w, const float* __restrict__ lin1_w,
                             __bf16* __restrict__ WT, float* __restrict__ svec) {
    int b = blockIdx.x;
    if (b < 64) {
        int i = b * 256 + threadIdx.x;        // 64*256 = 16384 = 2*NCOPY*128
        colpart[i] = 0.f;
        if (i < 32) out_head[i] = 0.f;
        if (i < NBKT) cursor[i] = 0;
    } else if (b < 64 + WPB) {
        int b2 = b - 64;                      // 0..511
        int mat = b2 >> 7, n = b2 & 127, k = threadIdx.x;
        if (k < 128) {
            const float* srcm = (mat < 3) ? (conv_w + (size_t)mat * 16384) : lin1_w;
            WT[((size_t)mat * 128 + n) * 128 + k] = (__bf16)srcm[(size_t)k * 128 + n];
        }
    } else {
        __shared__ float sv[256];             // svec = colsum of lin1_w rows 256..511, 256 thr
        int j = threadIdx.x & 127, g = threadIdx.x >> 7;
        float s = 0.f;
        for (int k = 256 + g * 128; k < 256 + g * 128 + 128; ++k)
            s += lin1_w[(size_t)k * 128 + j];
        sv[threadIdx.x] = s;
        __syncthreads();
        if (threadIdx.x < 128) svec[j] = sv[j] + sv[j + 128];
    }
}

// ---------------- CSR build pass 1: bucket scatter w/ dynamic cursor reservation ----------------
__global__ __launch_bounds__(256) void k_scatter(const int* __restrict__ src,
                                                 const int* __restrict__ dst,
                                                 const float* __restrict__ ew,
                                                 int* __restrict__ cursor,
                                                 uint2* __restrict__ ebuf) {
    __shared__ int c[NBKT], basee[NBKT];
    int t = threadIdx.x, b = blockIdx.x;
    if (t < NBKT) c[t] = 0;
    __syncthreads();
    int e0 = b * 1024;
    int myd[4], mybkt[4];
#pragma unroll
    for (int j = 0; j < 4; ++j) {
        int e = e0 + t + j * 256;
        mybkt[j] = -1;
        if (e < N_EDGES) {
            myd[j] = dst[e];
            mybkt[j] = myd[j] / BKT;
            atomicAdd(&c[mybkt[j]], 1);
        }
    }
    __syncthreads();
    if (t < NBKT && c[t] > 0) basee[t] = atomicAdd(&cursor[t], c[t]);
    __syncthreads();
    if (t < NBKT) c[t] = 0;   // reuse as local fill
    __syncthreads();
#pragma unroll
    for (int j = 0; j < 4; ++j) {
        if (mybkt[j] >= 0) {
            int e = e0 + t + j * 256;
            int bkt = mybkt[j];
            int dl = myd[j] - bkt * BKT;                 // < 392 -> 9 bits
            int pos = basee[bkt] + atomicAdd(&c[bkt], 1);
            if (pos < BREG)
                ebuf[(size_t)bkt * BREG + pos] =
                    make_uint2(((unsigned)dl << 17) | (unsigned)src[e], __float_as_uint(ew[e]));
        }
    }
}

// ---------------- CSR build pass 2: one block per bucket, LDS-staged permutation ---------------
// Counting + scan + dinv fused; final esn2 written COALESCED via LDS staging (kills the
// scattered-8B-write dirty-line problem that made the old k_build ~65 us).
__global__ __launch_bounds__(256) void k_build(const uint2* __restrict__ ebuf,
                                               const int* __restrict__ cursor,
                                               uint2* __restrict__ esn2,
                                               int* __restrict__ offs, int* __restrict__ cnt,
                                               float* __restrict__ dinv) {
    __shared__ uint2 stage[SCAP];             // 57 KB
    __shared__ int   cB[BKT];
    __shared__ float degB[BKT];
    __shared__ int   oB[BKT];
    __shared__ int   fillB[BKT];
    __shared__ int   p[256];
    int b = blockIdx.x, t = threadIdx.x;
    size_t base = (size_t)b * BREG;
    int num = min(cursor[b], BREG);
    for (int i = t; i < BKT; i += 256) { cB[i] = 0; degB[i] = 1.0f; fillB[i] = 0; }
    __syncthreads();
    for (int i = t; i < num; i += 256) {      // pass A: coalesced read + LDS hist
        uint2 eu = ebuf[base + i];
        int dl = eu.x >> 17;
        atomicAdd(&cB[dl], 1);
        atomicAdd(&degB[dl], __uint_as_float(eu.y));
    }
    __syncthreads();
    for (int i = t; i < BKT; i += 256) degB[i] = rsqrtf(degB[i]);   // now holds dinv
    // exclusive scan over 392 counters (2/thread, padded to 512)
    int c0 = (2 * t     < BKT) ? cB[2 * t]     : 0;
    int c1 = (2 * t + 1 < BKT) ? cB[2 * t + 1] : 0;
    int s0 = c0 + c1;
    p[t] = s0;
    __syncthreads();
    int own = s0;
    for (int d = 1; d < 256; d <<= 1) {
        int v = (t >= d) ? p[t - d] : 0;
        __syncthreads();
        p[t] += v;
        __syncthreads();
    }
    int e0 = p[t] - own;
    if (2 * t     < BKT) oB[2 * t]     = e0;
    if (2 * t + 1 < BKT) oB[2 * t + 1] = e0 + c0;
    __syncthreads();
    int nb0 = b * BKT;
    for (int i = t; i < BKT; i += 256) {
        int n = nb0 + i;
        if (n < N_NODES) {
            offs[n] = (int)base + oB[i];
            cnt[n] = cB[i];
            dinv[n] = degB[i];
        }
    }
    __syncthreads();
    for (int i = t; i < num; i += 256) {      // pass C: re-read (L2-hot), scatter into LDS
        uint2 eu = ebuf[base + i];
        int dl = eu.x >> 17;
        unsigned s = eu.x & 131071u;
        int slot = oB[dl] + atomicAdd(&fillB[dl], 1);
        uint2 val = make_uint2(s, __float_as_uint(__uint_as_float(eu.y) * degB[dl]));
        if (slot < SCAP) stage[slot] = val;
        else esn2[base + slot] = val;         // ~never taken (>11 sigma)
    }
    __syncthreads();
    int lim = min(num, SCAP);
    for (int i = t; i < lim; i += 256)        // pass D: coalesced global write
        esn2[base + i] = stage[i];
}

// ---------------- MFMA GEMM: C[n][128] = A'[n][128] @ W + bias ----------------
// AMODE 0: A = raw fp32 (x). AMODE 1: A = fp32 agg, fused BN+relu.
template <int AMODE>
__global__ __launch_bounds__(256) void k_gemm_mfma(const float* __restrict__ A,
                                                   const float* __restrict__ mean,
                                                   const float* __restrict__ rstd,
                                                   const __bf16* __restrict__ WT,
                                                   const float* __restrict__ bias,
                                                   __bf16* __restrict__ C, int nrows) {
    __shared__ __bf16 As[64 * PADK];
    __shared__ __bf16 Ws[128 * PADK];
    int t = threadIdx.x;
    int rowBase = blockIdx.x * 64;
    const uint4* WTg = (const uint4*)WT;
    for (int i = t; i < 2048; i += 256) {
        int n = i >> 4, k8 = i & 15;
        *(uint4*)&Ws[n * PADK + k8 * 8] = WTg[i];
    }
    const float4* A4 = (const float4*)A;
    const float4* M4 = (const float4*)mean;
    const float4* R4 = (const float4*)rstd;
    for (int i = t; i < 1024; i += 256) {
        int r = i >> 4, k8 = i & 15;
        int gr = rowBase + r;
        float4 a0 = make_float4(0.f, 0.f, 0.f, 0.f), a1 = a0;
        if (gr < nrows) {
            a0 = A4[(size_t)gr * 32 + k8 * 2];
            a1 = A4[(size_t)gr * 32 + k8 * 2 + 1];
        }
        if (AMODE == 1) {
            float4 m0 = M4[k8 * 2], m1 = M4[k8 * 2 + 1];
            float4 r0 = R4[k8 * 2], r1 = R4[k8 * 2 + 1];
            a0.x = fmaxf((a0.x - m0.x) * r0.x, 0.f); a0.y = fmaxf((a0.y - m0.y) * r0.y, 0.f);
            a0.z = fmaxf((a0.z - m0.z) * r0.z, 0.f); a0.w = fmaxf((a0.w - m0.w) * r0.w, 0.f);
            a1.x = fmaxf((a1.x - m1.x) * r1.x, 0.f); a1.y = fmaxf((a1.y - m1.y) * r1.y, 0.f);
            a1.z = fmaxf((a1.z - m1.z) * r1.z, 0.f); a1.w = fmaxf((a1.w - m1.w) * r1.w, 0.f);
        }
        bf16_8 o = { (__bf16)a0.x, (__bf16)a0.y, (__bf16)a0.z, (__bf16)a0.w,
                     (__bf16)a1.x, (__bf16)a1.y, (__bf16)a1.z, (__bf16)a1.w };
        *(bf16_8*)&As[r * PADK + k8 * 8] = o;
    }
    __syncthreads();
    int wave = t >> 6, lane = t & 63, quad = lane >> 4, m = lane & 15;
    int ar = wave * 16 + m;
    f32_4 acc[8];
#pragma unroll
    for (int i = 0; i < 8; ++i) acc[i] = (f32_4){0.f, 0.f, 0.f, 0.f};
#pragma unroll
    for (int kk = 0; kk < 4; ++kk) {
        bf16_8 a = *(const bf16_8*)&As[ar * PADK + kk * 32 + quad * 8];
#pragma unroll
        for (int n0 = 0; n0 < 8; ++n0) {
            bf16_8 b = *(const bf16_8*)&Ws[(n0 * 16 + m) * PADK + kk * 32 + quad * 8];
            acc[n0] = __builtin_amdgcn_mfma_f32_16x16x32_bf16(a, b, acc[n0], 0, 0, 0);
        }
    }
    __syncthreads();
#pragma unroll
    for (int n0 = 0; n0 < 8; ++n0) {
        int col = n0 * 16 + m;
        float bi = bias[col];
#pragma unroll
        for (int r = 0; r < 4; ++r) {
            int rr = wave * 16 + quad * 4 + r;
            As[rr * PADK + col] = (__bf16)(acc[n0][r] + bi);
        }
    }
    __syncthreads();
    uint4* Cg = (uint4*)C;
    for (int i = t; i < 1024; i += 256) {
        int r = i >> 4, k8 = i & 15;
        int gr = rowBase + r;
        if (gr < nrows) Cg[(size_t)gr * 16 + k8] = *(const uint4*)&As[r * PADK + k8 * 8];
    }
}

// ---------------- edge aggregation (unroll 8, chunked) + fused BN stats -------------------------
__global__ __launch_bounds__(256) void k_agg(const __bf16* __restrict__ hwb,
                                             const uint2* __restrict__ esn2,
                                             const int* __restrict__ offs,
                                             const int* __restrict__ cnt,
                                             const float* __restrict__ dinv,
                                             float* __restrict__ agg,
                                             float* __restrict__ colpart) {
    __shared__ float red1[4 * 128], red2[4 * 128];
    int t = threadIdx.x;
    int n = (blockIdx.x * 256 + t) >> 6;
    int lane = t & 63, wave = t >> 6;
    float2 acc = make_float2(0.f, 0.f);
    const unsigned int* hw32 = (const unsigned int*)hwb;
    if (n < N_NODES) {
        float dvn = dinv[n];
        float2 sv = bf2f2(hw32[(size_t)n * 64 + lane]);
        acc.x = sv.x * dvn * dvn; acc.y = sv.y * dvn * dvn;   // self-loop term
        int beg = offs[n], num = cnt[n];
        for (int ch = 0; ch < num; ch += 64) {
            int nn = min(64, num - ch);
            int s_l = 0; float w_l = 0.f;
            if (lane < nn) {
                uint2 e = esn2[beg + ch + lane];
                s_l = (int)e.x;
                w_l = dinv[s_l] * __uint_as_float(e.y);       // e.y = ew*dinv[dst]
            }
            int i = 0;
            for (; i + 8 <= nn; i += 8) {
                int ss[8]; float ww[8]; unsigned uu[8];
#pragma unroll
                for (int j = 0; j < 8; ++j) { ss[j] = __shfl(s_l, i + j); ww[j] = __shfl(w_l, i + j); }
#pragma unroll
                for (int j = 0; j < 8; ++j) uu[j] = hw32[(size_t)ss[j] * 64 + lane];
#pragma unroll
                for (int j = 0; j < 8; ++j) {
                    float2 f = bf2f2(uu[j]);
                    acc.x += f.x * ww[j]; acc.y += f.y * ww[j];
                }
            }
            for (; i < nn; ++i) {
                int s = __shfl(s_l, i);
                float w = __shfl(w_l, i);
                float2 f = bf2f2(hw32[(size_t)s * 64 + lane]);
                acc.x += f.x * w; acc.y += f.y * w;
            }
        }
        ((float2*)agg)[(size_t)n * 64 + lane] = acc;
    }
    *(float2*)&red1[wave * 128 + 2 * lane] = acc;
    *(float2*)&red2[wave * 128 + 2 * lane] = make_float2(acc.x * acc.x, acc.y * acc.y);
    __syncthreads();
    if (t < 128) {
        float s = red1[t] + red1[128 + t] + red1[256 + t] + red1[384 + t];
        float q = red2[t] + red2[128 + t] + red2[256 + t] + red2[384 + t];
        int c = blockIdx.x & (NCOPY - 1);
        unsafeAtomicAdd(&colpart[c * 128 + t], s);
        unsafeAtomicAdd(&colpart[NCOPY * 128 + c * 128 + t], q);
    }
}

// ---------------- bnfinal (parallel, 256 thr) + optional fused scoring-prep (layer 2) -----------
// Separate launch = cross-XCD visibility for colpart (R7 lesson).
template <int DO_PREP>
__global__ void k_bnfinal(float* __restrict__ colpart, float* __restrict__ mean,
                          float* __restrict__ rstd,
                          const float* __restrict__ agg, const int* __restrict__ cid,
                          const float* __restrict__ lin1w, const float* __restrict__ lin1b,
                          float* __restrict__ c0) {
    __shared__ float s1[256], s2[256], ms[128], rs[128], xc[128];
    int t = threadIdx.x;
    int j = t & 127, g = t >> 7;              // g in {0,1}: 32 copies each
    float s = 0.f, q = 0.f;
    for (int c = g * 32; c < g * 32 + 32; ++c) {
        s += colpart[c * 128 + j];
        q += colpart[NCOPY * 128 + c * 128 + j];
        colpart[c * 128 + j] = 0.f;           // ready for next layer
        colpart[NCOPY * 128 + c * 128 + j] = 0.f;
    }
    s1[t] = s; s2[t] = q;
    __syncthreads();
    if (t < 128) {
        float S = s1[t] + s1[t + 128];
        float Q = s2[t] + s2[t + 128];
        float m = S * (1.0f / N_NODES);
        float v = Q * (1.0f / N_NODES) - m * m;
        float r = rsqrtf(v + 1e-5f);
        mean[t] = m; rstd[t] = r;
        if (DO_PREP) { ms[t] = m; rs[t] = r; }
    }
    if (DO_PREP) {
        __syncthreads();
        int cn = cid[0];
        if (t < 128) xc[t] = fmaxf((agg[(size_t)cn * 128 + t] - ms[t]) * rs[t], 0.f);
        __syncthreads();
        float acc = g ? 0.f : lin1b[j];
        for (int k = g * 64; k < g * 64 + 64; ++k)
            acc += xc[k] * lin1w[(size_t)(128 + k) * 128 + j];
        s1[t] = acc;
        __syncthreads();
        if (t < 128) c0[t] = s1[t] + s1[t + 128];
    }
}

// ---------------- scoring: fused BN+relu staging (writes fp32 h) + MFMA + relu + dot(lin2)
//                  + fused partition pooling epilogue ------------------------------------------
__global__ __launch_bounds__(256) void k_score_mfma(const float* __restrict__ agg,
                                                    const float* __restrict__ mean,
                                                    const float* __restrict__ rstd,
                                                    const __bf16* __restrict__ WT,
                                                    const float* __restrict__ c0,
                                                    const float* __restrict__ svec,
                                                    const float* __restrict__ ecn,
                                                    const float* __restrict__ lin2w,
                                                    const float* __restrict__ lin2b,
                                                    const float* __restrict__ part,
                                                    float* __restrict__ out,
                                                    float* __restrict__ hout,
                                                    int nrows) {
    __shared__ __bf16 As[64 * PADK];
    __shared__ __bf16 Ws[128 * PADK];
    __shared__ float c0s[128], svs[128], l2s[128];
    __shared__ float sc[64], red[256];
    int t = threadIdx.x;
    int rowBase = blockIdx.x * 64;
    const uint4* WTg = (const uint4*)WT;
    for (int i = t; i < 2048; i += 256) {
        int n = i >> 4, k8 = i & 15;
        *(uint4*)&Ws[n * PADK + k8 * 8] = WTg[i];
    }
    const float4* A4 = (const float4*)agg;
    const float4* M4 = (const float4*)mean;
    const float4* R4 = (const float4*)rstd;
    float4* H4 = (float4*)hout;
    for (int i = t; i < 1024; i += 256) {
        int r = i >> 4, k8 = i & 15;
        int gr = rowBase + r;
        float4 a0 = make_float4(0.f, 0.f, 0.f, 0.f), a1 = a0;
        if (gr < nrows) {
            a0 = A4[(size_t)gr * 32 + k8 * 2];
            a1 = A4[(size_t)gr * 32 + k8 * 2 + 1];
        }
        float4 m0 = M4[k8 * 2], m1 = M4[k8 * 2 + 1];
        float4 r0 = R4[k8 * 2], r1 = R4[k8 * 2 + 1];
        float4 f0, f1;
        f0.x = fmaxf((a0.x - m0.x) * r0.x, 0.f); f0.y = fmaxf((a0.y - m0.y) * r0.y, 0.f);
        f0.z = fmaxf((a0.z - m0.z) * r0.z, 0.f); f0.w = fmaxf((a0.w - m0.w) * r0.w, 0.f);
        f1.x = fmaxf((a1.x - m1.x) * r1.x, 0.f); f1.y = fmaxf((a1.y - m1.y) * r1.y, 0.f);
        f1.z = fmaxf((a1.z - m1.z) * r1.z, 0.f); f1.w = fmaxf((a1.w - m1.w) * r1.w, 0.f);
        if (gr < nrows) {
            H4[(size_t)gr * 32 + k8 * 2] = f0;
            H4[(size_t)gr * 32 + k8 * 2 + 1] = f1;
        }
        bf16_8 o = { (__bf16)f0.x, (__bf16)f0.y, (__bf16)f0.z, (__bf16)f0.w,
                     (__bf16)f1.x, (__bf16)f1.y, (__bf16)f1.z, (__bf16)f1.w };
        *(bf16_8*)&As[r * PADK + k8 * 8] = o;
    }
    if (t < 128) { c0s[t] = c0[t]; svs[t] = svec[t]; l2s[t] = lin2w[t]; }
    __syncthreads();
    int wave = t >> 6, lane = t & 63, quad = lane >> 4, m = lane & 15;
    int ar = wave * 16 + m;
    f32_4 acc[8];
#pragma unroll
    for (int i = 0; i < 8; ++i) acc[i] = (f32_4){0.f, 0.f, 0.f, 0.f};
#pragma unroll
    for (int kk = 0; kk < 4; ++kk) {
        bf16_8 a = *(const bf16_8*)&As[ar * PADK + kk * 32 + quad * 8];
#pragma unroll
        for (int n0 = 0; n0 < 8; ++n0) {
            bf16_8 b = *(const bf16_8*)&Ws[(n0 * 16 + m) * PADK + kk * 32 + quad * 8];
            acc[n0] = __builtin_amdgcn_mfma_f32_16x16x32_bf16(a, b, acc[n0], 0, 0, 0);
        }
    }
    float l2b = lin2b[0];
#pragma unroll
    for (int r = 0; r < 4; ++r) {
        int row = rowBase + wave * 16 + quad * 4 + r;
        float e = (row < nrows) ? ecn[row] : 0.f;
        float partial = 0.f;
#pragma unroll
        for (int n0 = 0; n0 < 8; ++n0) {
            int col = n0 * 16 + m;
            float v = acc[n0][r] + c0s[col] + e * svs[col];
            partial += fmaxf(v, 0.f) * l2s[col];
        }
        partial += __shfl_xor(partial, 8, 16);
        partial += __shfl_xor(partial, 4, 16);
        partial += __shfl_xor(partial, 2, 16);
        partial += __shfl_xor(partial, 1, 16);
        if (m == 0) sc[wave * 16 + quad * 4 + r] = partial + l2b;
    }
    __syncthreads();
    // fused partition pooling: out[p] += sum_r sc[r]*part[row][p]
    int rg = t >> 5, pp = t & 31;
    float a = 0.f;
    for (int j = 0; j < 8; ++j) {
        int r = rg * 8 + j;
        int row = rowBase + r;
        if (row < nrows) a += sc[r] * part[(size_t)row * 32 + pp];
    }
    red[t] = a;
    __syncthreads();
    if (t < 32) {
        float s = 0.f;
        for (int i = 0; i < 8; ++i) s += red[i * 32 + t];
        unsafeAtomicAdd(&out[t], s);
    }
}

// ---------------- host ----------------
extern "C" void kernel_launch(void* const* d_in, const int* in_sizes, int n_in,
                              void* d_out, int out_size, void* d_ws, size_t ws_size,
                              hipStream_t stream) {
    const float* x        = (const float*)d_in[0];
    const int*   eidx     = (const int*)d_in[1];
    const float* ew       = (const float*)d_in[2];
    const float* parts    = (const float*)d_in[3];
    const float* ecn      = (const float*)d_in[5];
    const float* conv_w   = (const float*)d_in[6];
    const float* conv_b   = (const float*)d_in[7];
    const float* lin1_w   = (const float*)d_in[8];
    const float* lin1_b   = (const float*)d_in[9];
    const float* lin2_w   = (const float*)d_in[10];
    const float* lin2_b   = (const float*)d_in[11];
    const int*   cid      = (const int*)d_in[12];

    const int* src = eidx;
    const int* dst = eidx + N_EDGES;

    char* p = (char*)d_ws;
    auto alloc = [&](size_t bytes) { char* r = p; p += (bytes + 255) & ~size_t(255); return r; };
    int*    cursor  = (int*)alloc(NBKT * 4);
    uint2*  ebuf    = (uint2*)alloc((size_t)NBKT * BREG * 8);       // 8.4 MB bucket regions
    uint2*  esn2    = (uint2*)alloc((size_t)NBKT * BREG * 8);       // 8.4 MB node-sorted CSR
    int*    offs    = (int*)alloc(NP * 4);
    int*    cnt     = (int*)alloc(NP * 4);
    float*  dinv    = (float*)alloc(NP * 4);
    float*  colpart = (float*)alloc(2 * NCOPY * 128 * 4);
    float*  mean    = (float*)alloc(128 * 4);
    float*  rstd    = (float*)alloc(128 * 4);
    float*  c0      = (float*)alloc(128 * 4);
    float*  svec    = (float*)alloc(128 * 4);
    __bf16* WT      = (__bf16*)alloc(4 * 128 * 128 * 2);
    __bf16* hwb     = (__bf16*)alloc((size_t)N_NODES * 128 * 2);
    float*  agg     = (float*)alloc((size_t)N_NODES * 128 * 4);

    float* out_head = (float*)d_out;
    float* hbuf     = (float*)d_out + 32;

    const int GB = (N_NODES + 63) / 64;        // 782
    const int AB = (N_NODES * 64 + 255) / 256; // 12500

    k_init_wprep<<<64 + WPB + 1, 256, 0, stream>>>(colpart, out_head, cursor,
                                                   conv_w, lin1_w, WT, svec);
    k_scatter<<<HB, 256, 0, stream>>>(src, dst, ew, cursor, ebuf);
    k_build<<<NBKT, 256, 0, stream>>>(ebuf, cursor, esn2, offs, cnt, dinv);

    for (int l = 0; l < 3; ++l) {
        if (l == 0)
            k_gemm_mfma<0><<<GB, 256, 0, stream>>>(x, mean, rstd, WT, conv_b, hwb, N_NODES);
        else
            k_gemm_mfma<1><<<GB, 256, 0, stream>>>(agg, mean, rstd, WT + (size_t)l * 16384,
                                                   conv_b + (size_t)l * 128, hwb, N_NODES);
        k_agg<<<AB, 256, 0, stream>>>(hwb, esn2, offs, cnt, dinv, agg, colpart);
        if (l < 2)
            k_bnfinal<0><<<1, 256, 0, stream>>>(colpart, mean, rstd,
                                                agg, cid, lin1_w, lin1_b, c0);
        else
            k_bnfinal<1><<<1, 256, 0, stream>>>(colpart, mean, rstd,
                                                agg, cid, lin1_w, lin1_b, c0);
    }

    k_score_mfma<<<GB, 256, 0, stream>>>(agg, mean, rstd, WT + (size_t)3 * 16384, c0, svec,
                                         ecn, lin2_w, lin2_b, parts, out_head, hbuf, N_NODES);
}